// Round 1
// baseline (52374.164 us; speedup 1.0000x reference)
//
#include <hip/hip_runtime.h>
#include <hip/hip_bf16.h>
#include <math.h>

#define B_ 64
#define T_ 600
#define U_ 64
#define V_ 80
#define H_ 512
#define KA_ 10
#define KO_ 20

__device__ __forceinline__ float sigmf(float x){ return 1.0f/(1.0f+expf(-x)); }

// Fused pipelined LSTM step: blocks [0,256) -> layer0 step tau, [256,512) -> layer1 step tau-1,
// [512,768) -> layer2 step tau-2. Each WG owns 2 hidden units j, all 64 batch entries.
// Thread map: tid = b + 64*sl; sl: 0=(j0,Xpart) 1=(j1,Xpart) 2=(j0,Hpart) 3=(j1,Hpart).
// Activations stored transposed [t][k][b] so lanes (=b) are coalesced.
__global__ __launch_bounds__(256) void k_lstm3(
    int tau,
    const float* __restrict__ strokes,
    const float* attn_t,
    const float* __restrict__ W0ih, const float* __restrict__ W0hh, const float* __restrict__ b0,
    const float* __restrict__ W1ih, const float* __restrict__ W1hh, const float* __restrict__ b1,
    const float* __restrict__ W2ih, const float* __restrict__ W2hh, const float* __restrict__ b2,
    float* out0, float* out1, float* out2,
    float* c0, float* c1, float* c2)
{
    int layer = blockIdx.x >> 8;
    int wg    = blockIdx.x & 255;
    int t     = tau - layer;
    if (t < 0 || t >= T_) return;

    const float* Wih; const float* Whh; const float* bias;
    const float* xprev; float* outp; float* cst; int Lx; int astep;
    if (layer == 0){ Wih=W0ih; Whh=W0hh; bias=b0; xprev=nullptr; outp=out0; cst=c0; Lx=3+V_;     astep=t-1; }
    else if (layer == 1){ Wih=W1ih; Whh=W1hh; bias=b1; xprev=out0; outp=out1; cst=c1; Lx=3+V_+H_; astep=t; }
    else { Wih=W2ih; Whh=W2hh; bias=b2; xprev=out1; outp=out2; cst=c2; Lx=3+V_+H_; astep=t; }

    int tid = threadIdx.x;
    int b   = tid & 63;
    int sl  = tid >> 6;        // wave id
    int jl  = sl & 1;
    int ks  = sl >> 1;         // 0: X part, 1: H part
    int j   = wg*2 + jl;

    float acc0=0.f, acc1=0.f, acc2=0.f, acc3=0.f;

    if (ks == 0){
        const float* w0 = Wih + (size_t)(0*H_+j)*Lx;
        const float* w1 = Wih + (size_t)(1*H_+j)*Lx;
        const float* w2 = Wih + (size_t)(2*H_+j)*Lx;
        const float* w3 = Wih + (size_t)(3*H_+j)*Lx;
        // strokes (B,T,3)
        const float* sr = strokes + ((size_t)b*T_ + t)*3;
        float x0=sr[0], x1=sr[1], x2=sr[2];
        acc0 = x0*w0[0] + x1*w0[1] + x2*w0[2];
        acc1 = x0*w1[0] + x1*w1[1] + x2*w1[2];
        acc2 = x0*w2[0] + x1*w2[1] + x2*w2[2];
        acc3 = x0*w3[0] + x1*w3[1] + x2*w3[2];
        if (astep >= 0){
            const float* ap = attn_t + (size_t)astep*V_*B_ + b;
            #pragma unroll 8
            for (int v=0; v<V_; ++v){
                float av = ap[(size_t)v*B_];
                acc0 += av*w0[3+v]; acc1 += av*w1[3+v]; acc2 += av*w2[3+v]; acc3 += av*w3[3+v];
            }
        }
        if (xprev){
            const float* xp = xprev + (size_t)t*H_*B_ + b;
            #pragma unroll 8
            for (int k=0; k<H_; ++k){
                float xv = xp[(size_t)k*B_];
                acc0 += xv*w0[83+k]; acc1 += xv*w1[83+k]; acc2 += xv*w2[83+k]; acc3 += xv*w3[83+k];
            }
        }
    } else {
        if (t > 0){
            const float* hp = outp + (size_t)(t-1)*H_*B_ + b;
            const float4* r0 = (const float4*)(Whh + (size_t)(0*H_+j)*H_);
            const float4* r1 = (const float4*)(Whh + (size_t)(1*H_+j)*H_);
            const float4* r2 = (const float4*)(Whh + (size_t)(2*H_+j)*H_);
            const float4* r3 = (const float4*)(Whh + (size_t)(3*H_+j)*H_);
            #pragma unroll 4
            for (int k=0; k<H_; k+=4){
                float h0 = hp[(size_t)(k+0)*B_];
                float h1 = hp[(size_t)(k+1)*B_];
                float h2 = hp[(size_t)(k+2)*B_];
                float h3 = hp[(size_t)(k+3)*B_];
                float4 q0 = r0[k>>2], q1 = r1[k>>2], q2 = r2[k>>2], q3 = r3[k>>2];
                acc0 += h0*q0.x + h1*q0.y + h2*q0.z + h3*q0.w;
                acc1 += h0*q1.x + h1*q1.y + h2*q1.z + h3*q1.w;
                acc2 += h0*q2.x + h1*q2.y + h2*q2.z + h3*q2.w;
                acc3 += h0*q3.x + h1*q3.y + h2*q3.z + h3*q3.w;
            }
        }
    }

    __shared__ float part[4][4][64];
    part[sl][0][b]=acc0; part[sl][1][b]=acc1; part[sl][2][b]=acc2; part[sl][3][b]=acc3;
    __syncthreads();

    if (sl < 2){
        int jj = wg*2 + sl;
        float gi = part[sl][0][b] + part[sl+2][0][b] + bias[0*H_+jj];
        float gf = part[sl][1][b] + part[sl+2][1][b] + bias[1*H_+jj];
        float gg = part[sl][2][b] + part[sl+2][2][b] + bias[2*H_+jj];
        float go = part[sl][3][b] + part[sl+2][3][b] + bias[3*H_+jj];
        float cold = (t==0) ? 0.f : cst[(size_t)jj*B_+b];
        float cnew = sigmf(gf)*cold + sigmf(gi)*tanhf(gg);
        cst[(size_t)jj*B_+b] = cnew;
        outp[((size_t)t*H_+jj)*B_+b] = sigmf(go)*tanhf(cnew);
    }
}

// Graves attention window for step t. One 64-thread WG per batch entry.
__global__ __launch_bounds__(64) void k_window(
    int t,
    const float* out0, const float* __restrict__ winW, const float* __restrict__ winb,
    const int* __restrict__ char_seq, const float* __restrict__ char_mask,
    float* attn_t, float* kst)
{
    int b = blockIdx.x; int tid = threadIdx.x;
    __shared__ float sa[KA_], sb_[KA_], sk[KA_], sphi[U_];
    __shared__ int   sseq[U_];
    __shared__ float smask[U_];

    sseq[tid]  = char_seq[b*U_+tid];
    smask[tid] = char_mask[b*U_+tid];

    if (tid < 3*KA_){
        const float* hrow = out0 + (size_t)t*H_*B_ + b;
        const float* wr   = winW + (size_t)tid*H_;
        float p = winb[tid];
        #pragma unroll 8
        for (int k=0; k<H_; ++k) p += hrow[(size_t)k*B_]*wr[k];
        float e = expf(p);
        if (tid < KA_) sa[tid] = e;
        else if (tid < 2*KA_) sb_[tid-KA_] = e;
        else {
            int a = tid - 2*KA_;
            float kn = ((t==0) ? 0.f : kst[a*B_+b]) + e;
            kst[a*B_+b] = kn;
            sk[a] = kn;
        }
    }
    __syncthreads();

    {
        int u = tid;
        float acc = 0.f;
        #pragma unroll
        for (int a=0; a<KA_; ++a){
            float d = sk[a] - (float)u;
            acc += sa[a]*expf(-sb_[a]*d*d);
        }
        // reference applies mask to phi AND bakes mask into char_oh
        sphi[u] = acc * smask[u] * smask[u];
    }
    __syncthreads();

    for (int v=tid; v<V_; v+=64){
        float wv = 0.f;
        for (int u=0; u<U_; ++u) wv += (sseq[u]==v) ? sphi[u] : 0.f;
        attn_t[((size_t)t*V_+v)*B_+b] = wv;
    }
}

// Final projection: final[t][g][b] = concat(out0,out1,out2)[t][:][b] . fcW[g,:] + fcb[g]
__global__ __launch_bounds__(256) void k_fc(
    const float* out0, const float* out1, const float* out2,
    const float* __restrict__ fcW, const float* __restrict__ fcb, float* finalb)
{
    int t = blockIdx.x; int tid = threadIdx.x;
    int b = tid & 63; int gq = tid >> 6;
    __shared__ float acts[128][B_];
    float acc[31];
    #pragma unroll
    for (int i=0; i<31; ++i) acc[i] = 0.f;

    const float* outs[3] = {out0, out1, out2};
    for (int seg=0; seg<3; ++seg){
        const float* o = outs[seg] + (size_t)t*H_*B_;
        for (int kc=0; kc<H_; kc+=128){
            __syncthreads();
            for (int i=tid; i<128*B_; i+=256){
                int k = i>>6, bb = i&63;
                acts[k][bb] = o[(size_t)(kc+k)*B_ + bb];
            }
            __syncthreads();
            for (int kk=0; kk<128; ++kk){
                float a = acts[kk][b];
                int K = seg*H_ + kc + kk;
                #pragma unroll
                for (int i=0; i<30; ++i)
                    acc[i] += a * fcW[(size_t)(gq+4*i)*1536 + K];
                if (gq == 0)
                    acc[30] += a * fcW[(size_t)120*1536 + K];
            }
        }
    }
    for (int i=0; i<30; ++i){
        int g = gq + 4*i;
        finalb[((size_t)t*121+g)*B_+b] = acc[i] + fcb[g];
    }
    if (gq == 0)
        finalb[((size_t)t*121+120)*B_+b] = acc[30] + fcb[120];
}

// Output transforms + scatter into d_out (concat of log_pi, myu, log_sigma, rho, eos)
__global__ __launch_bounds__(256) void k_transform(const float* __restrict__ finalb, float* __restrict__ out)
{
    int idx = blockIdx.x*256 + threadIdx.x;   // t*64 + b
    int t = idx >> 6; int b = idx & 63;
    const float* f = finalb + (size_t)t*121*B_ + b;
    size_t bt = (size_t)b*T_ + t;

    float* myu = out + 768000;
    #pragma unroll
    for (int i=0; i<40; ++i) myu[bt*40 + i] = f[(size_t)i*B_];

    float* lsg = out + 2304000;
    #pragma unroll
    for (int i=0; i<40; ++i) lsg[bt*40 + i] = f[(size_t)(40+i)*B_];

    float pi[KO_];
    float m = -1e30f;
    #pragma unroll
    for (int ko=0; ko<KO_; ++ko){ pi[ko] = f[(size_t)(80+ko)*B_]; m = fmaxf(m, pi[ko]); }
    float s = 0.f;
    #pragma unroll
    for (int ko=0; ko<KO_; ++ko) s += expf(pi[ko]-m);
    float lse = m + logf(s);
    #pragma unroll
    for (int ko=0; ko<KO_; ++ko) out[bt*20 + ko] = pi[ko] - lse;

    float* rho = out + 3840000;
    #pragma unroll
    for (int ko=0; ko<KO_; ++ko) rho[bt*20 + ko] = tanhf(f[(size_t)(100+ko)*B_]);

    out[4608000 + bt] = 1.f/(1.f + expf(f[(size_t)120*B_]));
}

extern "C" void kernel_launch(void* const* d_in, const int* in_sizes, int n_in,
                              void* d_out, int out_size, void* d_ws, size_t ws_size,
                              hipStream_t stream)
{
    const int*   char_seq  = (const int*)  d_in[0];
    const float* char_mask = (const float*)d_in[1];
    const float* strokes   = (const float*)d_in[2];
    const float* W0ih = (const float*)d_in[4];
    const float* W0hh = (const float*)d_in[5];
    const float* b0   = (const float*)d_in[6];
    const float* winW = (const float*)d_in[7];
    const float* winb = (const float*)d_in[8];
    const float* W1ih = (const float*)d_in[9];
    const float* W1hh = (const float*)d_in[10];
    const float* b1   = (const float*)d_in[11];
    const float* W2ih = (const float*)d_in[12];
    const float* W2hh = (const float*)d_in[13];
    const float* b2   = (const float*)d_in[14];
    const float* fcW  = (const float*)d_in[15];
    const float* fcb  = (const float*)d_in[16];

    float* ws    = (float*)d_ws;
    float* out0  = ws;                      // [T][H][B] 19,660,800
    float* out1  = out0 + 19660800;
    float* out2  = out1 + 19660800;
    float* attn  = out2 + 19660800;         // [T][V][B]  3,072,000
    float* c0    = attn + 3072000;          // [H][B] 32768
    float* c1    = c0 + 32768;
    float* c2    = c1 + 32768;
    float* kst   = c2 + 32768;              // [KA][B] 640
    float* finalb= kst + 640;               // [T][121][B] 4,646,400

    for (int tau=0; tau<T_+2; ++tau){
        hipLaunchKernelGGL(k_lstm3, dim3(768), dim3(256), 0, stream, tau,
            strokes, attn, W0ih, W0hh, b0, W1ih, W1hh, b1, W2ih, W2hh, b2,
            out0, out1, out2, c0, c1, c2);
        if (tau < T_)
            hipLaunchKernelGGL(k_window, dim3(64), dim3(64), 0, stream, tau,
                out0, winW, winb, char_seq, char_mask, attn, kst);
    }
    hipLaunchKernelGGL(k_fc, dim3(600), dim3(256), 0, stream, out0, out1, out2, fcW, fcb, finalb);
    hipLaunchKernelGGL(k_transform, dim3(150), dim3(256), 0, stream, finalb, (float*)d_out);
}